// Round 6
// baseline (431.075 us; speedup 1.0000x reference)
//
#include <hip/hip_runtime.h>

// AdderNet forward:  x[256,1,64,64] -> adder(w1)+BN+ReLU -> adder(w2)+BN+ReLU
//                    -> avgpool -> FC -> out[256,10]
// R6: 4-position threads in k_layer2. R5 analysis: true VALU issue ~49%
// (reported 98% is gfx94x-formula 2x inflated); the other half is lgkmcnt(0)
// drains on per-c s_load weight batches. 4-pos threads halve weight-load
// frequency per math op (72 s_loads per 576 math, was per 288), single
// og-pass, no double-buffer movs. Row stride 68 (16B-aligned b128 reads).

#define BATCH 256
#define HW 4096

// ---------------- Kernel 1: layer-1 stats (sum, sumsq per channel) ----------
__global__ __launch_bounds__(256) void k_stats1(const float* __restrict__ x,
                                                const float* __restrict__ w1,
                                                double* __restrict__ s1) {
  __shared__ float sx[66 * 66];
  __shared__ float red[4 * 16 * 2];
  int b = blockIdx.x, tid = threadIdx.x;
  const float* xb = x + b * HW;
  for (int i = tid; i < 66 * 66; i += 256) {
    int r = i / 66, cc = i - r * 66;
    int ry = r - 1, rx = cc - 1;
    sx[i] = (ry >= 0 && ry < 64 && rx >= 0 && rx < 64) ? xb[ry * 64 + rx] : 0.f;
  }
  __syncthreads();
  float tsum[16], tsq[16];
#pragma unroll
  for (int c = 0; c < 16; c++) { tsum[c] = 0.f; tsq[c] = 0.f; }
  for (int g = 0; g < 2; g++) {
    float wv[8][9];
#pragma unroll
    for (int c = 0; c < 8; c++)
#pragma unroll
      for (int t = 0; t < 9; t++) wv[c][t] = w1[(g * 8 + c) * 9 + t];
    for (int p = 0; p < 16; p++) {
      int pix = tid + p * 256;
      int y = pix >> 6, xx = pix & 63;
      float pa[9];
#pragma unroll
      for (int dy = 0; dy < 3; dy++)
#pragma unroll
        for (int dx = 0; dx < 3; dx++)
          pa[dy * 3 + dx] = sx[(y + dy) * 66 + xx + dx];
#pragma unroll
      for (int c = 0; c < 8; c++) {
        float acc = 0.f;
#pragma unroll
        for (int t = 0; t < 9; t++) acc += fabsf(pa[t] - wv[c][t]);
        float v = -acc;
        tsum[g * 8 + c] += v;
        tsq[g * 8 + c] += v * v;
      }
    }
  }
  int lane = tid & 63, wid = tid >> 6;
#pragma unroll
  for (int c = 0; c < 16; c++) {
    float s = tsum[c], q = tsq[c];
    for (int off = 32; off; off >>= 1) {
      s += __shfl_down(s, off, 64);
      q += __shfl_down(q, off, 64);
    }
    if (lane == 0) { red[(wid * 16 + c) * 2] = s; red[(wid * 16 + c) * 2 + 1] = q; }
  }
  __syncthreads();
  if (tid < 16) {
    float s = red[tid * 2] + red[(16 + tid) * 2] + red[(32 + tid) * 2] + red[(48 + tid) * 2];
    float q = red[tid * 2 + 1] + red[(16 + tid) * 2 + 1] + red[(32 + tid) * 2 + 1] +
              red[(48 + tid) * 2 + 1];
    atomicAdd(&s1[tid], (double)s);
    atomicAdd(&s1[16 + tid], (double)q);
  }
}

// ---------------- Kernel 2: layer 2 (the heavy one) -------------------------
// Block = (image b, 4-row band). Stage 0: inline BN1 params. Stage 1: h1 tile
// into LDS (stride-68 rows, 16B aligned). Stage 2: single pass; wave wid
// owns outputs wid*8..+7; lane = (row, 4-col span); acc[8][4].
__global__ __launch_bounds__(256, 4) void k_layer2(
    const float* __restrict__ x, const float* __restrict__ w1,
    const double* __restrict__ s1, const float* __restrict__ g1,
    const float* __restrict__ b1, const float* __restrict__ w2,
    float* __restrict__ a2, double* __restrict__ s2) {
  __shared__ float sxt[8 * 68];        // x rows y0-2..y0+5, cols -2..65
  __shared__ float sh[16 * 6 * 68];    // h1 [c][row y0-1..y0+4][col -1..66]
  __shared__ float red[4 * 16];        // per-wave stats partials (s,q)
  __shared__ float sc1s[16], sf1s[16];
  int blk = blockIdx.x;
  int b = blk >> 4, rb = blk & 15;
  int y0 = rb * 4;
  int tid = threadIdx.x;

  if (tid < 16) {  // inline BN1 params (block-redundant)
    double N = 1048576.0;
    double mean = s1[tid] / N;
    double var = s1[16 + tid] / N - mean * mean;
    float inv = (float)(1.0 / sqrt(var + 1e-5));
    float sc = g1[tid] * inv;
    sc1s[tid] = sc;
    sf1s[tid] = b1[tid] - (float)mean * sc;
  }
  const float* xb = x + b * HW;
  for (int i = tid; i < 8 * 68; i += 256) {
    int r = i / 68, cc = i - r * 68;
    int ry = y0 + r - 2, rx = cc - 2;
    sxt[i] = (ry >= 0 && ry < 64 && rx >= 0 && rx < 64) ? xb[ry * 64 + rx] : 0.f;
  }
  __syncthreads();
  // h1 recompute (same summation order as k_stats1 -> bit-identical)
  for (int c = 0; c < 16; c++) {
    float wv[9];
#pragma unroll
    for (int t = 0; t < 9; t++) wv[t] = w1[c * 9 + t];
    float sc = sc1s[c], sf = sf1s[c];
    for (int i = tid; i < 408; i += 256) {
      int r = i / 68, col = i - r * 68;
      int y = y0 + r - 1, xx = col - 1;  // col 0..67 -> x -1..66
      float v = 0.f;  // h1 padding is post-activation zero
      if (y >= 0 && y < 64 && xx >= 0 && xx < 64) {
        float acc = 0.f;
#pragma unroll
        for (int dy = 0; dy < 3; dy++)
#pragma unroll
          for (int dx = 0; dx < 3; dx++)
            acc += fabsf(sxt[(r + dy) * 68 + col + dx] - wv[dy * 3 + dx]);
        v = fmaxf(fmaf(-acc, sc, sf), 0.f);
      }
      sh[c * 408 + i] = v;
    }
  }
  __syncthreads();

  int lane = tid & 63, wid = tid >> 6;
  int r = lane >> 4;          // row within band, 0..3
  int x0 = (lane & 15) * 4;   // col span start, 0..60 (16B-aligned reads)
  int ob = __builtin_amdgcn_readfirstlane(wid * 8);  // wave's output base
  const float* shp = &sh[r * 68 + x0];
  float* a2p = a2 + (size_t)b * 32 * HW + (y0 + r) * 64 + x0;

  float acc[8][4];
#pragma unroll
  for (int o = 0; o < 8; o++)
#pragma unroll
    for (int p = 0; p < 4; p++) acc[o][p] = 0.f;

#pragma unroll 1
  for (int c = 0; c < 16; c++) {
    // activations: 6 floats per dy row (positions x0-1 .. x0+4)
    float a[3][6];
#pragma unroll
    for (int dy = 0; dy < 3; dy++) {
      const float* rp = shp + c * 408 + dy * 68;
      float4 q = *(const float4*)rp;
      float2 t = *(const float2*)(rp + 4);
      a[dy][0] = q.x; a[dy][1] = q.y; a[dy][2] = q.z; a[dy][3] = q.w;
      a[dy][4] = t.x; a[dy][5] = t.y;
    }
    // weights: wave-uniform -> s_load batch (8 o x 9)
    const float* wc = w2 + ob * 144 + c * 9;
    float w[8][9];
#pragma unroll
    for (int o = 0; o < 8; o++)
#pragma unroll
      for (int t = 0; t < 9; t++) w[o][t] = wc[o * 144 + t];
#pragma unroll
    for (int o = 0; o < 8; o++)
#pragma unroll
      for (int dy = 0; dy < 3; dy++) {
        float w0 = w[o][dy * 3], w1v = w[o][dy * 3 + 1], w2v = w[o][dy * 3 + 2];
#pragma unroll
        for (int p = 0; p < 4; p++)
          acc[o][p] += fabsf(a[dy][p] - w0) + fabsf(a[dy][p + 1] - w1v) +
                       fabsf(a[dy][p + 2] - w2v);
      }
  }

  // store + per-wave stats partials (each o owned by exactly one wave)
#pragma unroll
  for (int o = 0; o < 8; o++) {
    float v0 = -acc[o][0], v1 = -acc[o][1], v2 = -acc[o][2], v3 = -acc[o][3];
    *(float4*)(a2p + (ob + o) * HW) = make_float4(v0, v1, v2, v3);
    float s = v0 + v1 + v2 + v3;
    float q = v0 * v0 + v1 * v1 + v2 * v2 + v3 * v3;
    for (int off = 32; off; off >>= 1) {
      s += __shfl_down(s, off, 64);
      q += __shfl_down(q, off, 64);
    }
    if (lane == 0) { red[wid * 16 + o * 2] = s; red[wid * 16 + o * 2 + 1] = q; }
  }
  __syncthreads();
  if (tid < 32) {
    int o = tid;
    float s = red[(o >> 3) * 16 + (o & 7) * 2];
    float q = red[(o >> 3) * 16 + (o & 7) * 2 + 1];
    atomicAdd(&s2[o], (double)s);
    atomicAdd(&s2[32 + o], (double)q);
  }
}

// ---------------- Kernel 3: BN2 (inline params) + ReLU + avgpool + FC -------
__global__ __launch_bounds__(1024) void k_poolfc(const float* __restrict__ a2,
                                                 const double* __restrict__ s2,
                                                 const float* __restrict__ g2,
                                                 const float* __restrict__ b2,
                                                 const float* __restrict__ fw,
                                                 const float* __restrict__ fb,
                                                 float* __restrict__ out) {
  __shared__ float sc2s[32], sf2s[32];
  __shared__ float poolv[32];
  int b = blockIdx.x, tid = threadIdx.x;
  if (tid < 32) {  // inline BN2 params (block-redundant)
    double N = 1048576.0;
    double mean = s2[tid] / N;
    double var = s2[32 + tid] / N - mean * mean;
    float inv = (float)(1.0 / sqrt(var + 1e-5));
    float sc = g2[tid] * inv;
    sc2s[tid] = sc;
    sf2s[tid] = b2[tid] - (float)mean * sc;
  }
  __syncthreads();
  int o = tid >> 5, part = tid & 31;  // 32 threads per channel
  const float4* p = (const float4*)(a2 + ((size_t)b * 32 + o) * HW);
  float s = sc2s[o], f = sf2s[o];
  float acc = 0.f;
#pragma unroll
  for (int i = 0; i < 32; i++) {  // 32 iters * 32 threads * 4 = 4096
    float4 v = p[i * 32 + part];
    acc += fmaxf(fmaf(v.x, s, f), 0.f) + fmaxf(fmaf(v.y, s, f), 0.f) +
           fmaxf(fmaf(v.z, s, f), 0.f) + fmaxf(fmaf(v.w, s, f), 0.f);
  }
  acc += __shfl_down(acc, 16, 32);
  acc += __shfl_down(acc, 8, 32);
  acc += __shfl_down(acc, 4, 32);
  acc += __shfl_down(acc, 2, 32);
  acc += __shfl_down(acc, 1, 32);
  if (part == 0) poolv[o] = acc * (1.f / 4096.f);
  __syncthreads();
  if (tid < 10) {
    float rr = fb[tid];
#pragma unroll
    for (int oc = 0; oc < 32; oc++) rr += poolv[oc] * fw[tid * 32 + oc];
    out[b * 10 + tid] = rr;
  }
}

extern "C" void kernel_launch(void* const* d_in, const int* in_sizes, int n_in,
                              void* d_out, int out_size, void* d_ws, size_t ws_size,
                              hipStream_t stream) {
  const float* x   = (const float*)d_in[0];
  const float* w1  = (const float*)d_in[1];
  const float* g1  = (const float*)d_in[2];
  const float* b1  = (const float*)d_in[3];
  const float* w2  = (const float*)d_in[4];
  const float* g2  = (const float*)d_in[5];
  const float* b2  = (const float*)d_in[6];
  const float* fcw = (const float*)d_in[7];
  const float* fcb = (const float*)d_in[8];
  float* out = (float*)d_out;

  char* ws = (char*)d_ws;
  float* a2 = (float*)ws;                                  // 134,217,728 B
  double* stats = (double*)(ws + 134217728);               // 96 doubles
  double* s1 = stats;                                      // sum[16], sq[16]
  double* s2 = stats + 32;                                 // sum[32], sq[32]

  hipMemsetAsync(stats, 0, 768, stream);
  k_stats1<<<256, 256, 0, stream>>>(x, w1, s1);
  k_layer2<<<4096, 256, 0, stream>>>(x, w1, s1, g1, b1, w2, a2, s2);
  k_poolfc<<<256, 1024, 0, stream>>>(a2, s2, g2, b2, fcw, fcb, out);
}

// Round 8
// 414.973 us; speedup vs baseline: 1.0388x; 1.0388x over previous
//
#include <hip/hip_runtime.h>
#include <hip/hip_fp16.h>

// AdderNet forward:  x[256,1,64,64] -> adder(w1)+BN+ReLU -> adder(w2)+BN+ReLU
//                    -> avgpool -> FC -> out[256,10]
// R8: R5's proven 3-kernel structure (best: 413us total, layer2 338) + fp16
// a2 (halves write traffic + poolfc read). R7's cooperative single-kernel
// NEVER RAN under graph capture (absmax = stub signature) -- do not use
// hipLaunchCooperativeKernel in this harness.
// BN2 stats stay fp32-exact (register accumulators); only the a2 store is
// rounded. Pool's 4096-avg crushes i.i.d. fp16 rounding to ~1e-4.

#define BATCH 256
#define HW 4096

// ---------------- Kernel 1: layer-1 stats (sum, sumsq per channel) ----------
__global__ __launch_bounds__(256) void k_stats1(const float* __restrict__ x,
                                                const float* __restrict__ w1,
                                                double* __restrict__ s1) {
  __shared__ float sx[66 * 66];
  __shared__ float red[4 * 16 * 2];
  int b = blockIdx.x, tid = threadIdx.x;
  const float* xb = x + b * HW;
  for (int i = tid; i < 66 * 66; i += 256) {
    int r = i / 66, cc = i - r * 66;
    int ry = r - 1, rx = cc - 1;
    sx[i] = (ry >= 0 && ry < 64 && rx >= 0 && rx < 64) ? xb[ry * 64 + rx] : 0.f;
  }
  __syncthreads();
  float tsum[16], tsq[16];
#pragma unroll
  for (int c = 0; c < 16; c++) { tsum[c] = 0.f; tsq[c] = 0.f; }
  for (int g = 0; g < 2; g++) {
    float wv[8][9];
#pragma unroll
    for (int c = 0; c < 8; c++)
#pragma unroll
      for (int t = 0; t < 9; t++) wv[c][t] = w1[(g * 8 + c) * 9 + t];
    for (int p = 0; p < 16; p++) {
      int pix = tid + p * 256;
      int y = pix >> 6, xx = pix & 63;
      float pa[9];
#pragma unroll
      for (int dy = 0; dy < 3; dy++)
#pragma unroll
        for (int dx = 0; dx < 3; dx++)
          pa[dy * 3 + dx] = sx[(y + dy) * 66 + xx + dx];
#pragma unroll
      for (int c = 0; c < 8; c++) {
        float acc = 0.f;
#pragma unroll
        for (int t = 0; t < 9; t++) acc += fabsf(pa[t] - wv[c][t]);
        float v = -acc;
        tsum[g * 8 + c] += v;
        tsq[g * 8 + c] += v * v;
      }
    }
  }
  int lane = tid & 63, wid = tid >> 6;
#pragma unroll
  for (int c = 0; c < 16; c++) {
    float s = tsum[c], q = tsq[c];
    for (int off = 32; off; off >>= 1) {
      s += __shfl_down(s, off, 64);
      q += __shfl_down(q, off, 64);
    }
    if (lane == 0) { red[(wid * 16 + c) * 2] = s; red[(wid * 16 + c) * 2 + 1] = q; }
  }
  __syncthreads();
  if (tid < 16) {
    float s = red[tid * 2] + red[(16 + tid) * 2] + red[(32 + tid) * 2] + red[(48 + tid) * 2];
    float q = red[tid * 2 + 1] + red[(16 + tid) * 2 + 1] + red[(32 + tid) * 2 + 1] +
              red[(48 + tid) * 2 + 1];
    atomicAdd(&s1[tid], (double)s);
    atomicAdd(&s1[16 + tid], (double)q);
  }
}

// ---------------- Kernel 2: layer 2 (the heavy one) -------------------------
// Block = (image b, 4-row band). Stage 0: inline BN1 params. Stage 1: h1 tile
// (rows y0-1..y0+4) into LDS. Stage 2: wave-pair og split; 2 og-passes of
// 8 outputs x 2 positions; activation reads register-double-buffered.
// a2 stored as fp16 (stats stay fp32-exact).
__global__ __launch_bounds__(256, 5) void k_layer2(
    const float* __restrict__ x, const float* __restrict__ w1,
    const double* __restrict__ s1, const float* __restrict__ g1,
    const float* __restrict__ b1, const float* __restrict__ w2,
    __half* __restrict__ a2, double* __restrict__ s2) {
  __shared__ float sxt[8 * 68];        // x rows y0-2..y0+5, cols -2..65
  __shared__ float sh[16 * 6 * 66];    // h1 [c][row y0-1..y0+4][col -1..64]
  __shared__ float red[4 * 32];        // per-wave stats partials (s,q)
  __shared__ float sc1s[16], sf1s[16];
  int blk = blockIdx.x;
  int b = blk >> 4, rb = blk & 15;
  int y0 = rb * 4;
  int tid = threadIdx.x;

  if (tid < 16) {  // inline BN1 params (block-redundant)
    double N = 1048576.0;
    double mean = s1[tid] / N;
    double var = s1[16 + tid] / N - mean * mean;
    float inv = (float)(1.0 / sqrt(var + 1e-5));
    float sc = g1[tid] * inv;
    sc1s[tid] = sc;
    sf1s[tid] = b1[tid] - (float)mean * sc;
  }
  const float* xb = x + b * HW;
  for (int i = tid; i < 8 * 68; i += 256) {
    int r = i / 68, cc = i - r * 68;
    int ry = y0 + r - 2, rx = cc - 2;
    sxt[i] = (ry >= 0 && ry < 64 && rx >= 0 && rx < 64) ? xb[ry * 64 + rx] : 0.f;
  }
  __syncthreads();
  // h1 recompute (same summation order as k_stats1)
  for (int c = 0; c < 16; c++) {
    float wv[9];
#pragma unroll
    for (int t = 0; t < 9; t++) wv[t] = w1[c * 9 + t];
    float sc = sc1s[c], sf = sf1s[c];
    for (int i = tid; i < 396; i += 256) {
      int r = i / 66, col = i - r * 66;
      int y = y0 + r - 1, xx = col - 1;
      float v = 0.f;  // h1 padding is post-activation zero
      if (y >= 0 && y < 64 && xx >= 0 && xx < 64) {
        float acc = 0.f;
#pragma unroll
        for (int dy = 0; dy < 3; dy++)
#pragma unroll
          for (int dx = 0; dx < 3; dx++)
            acc += fabsf(sxt[(r + dy) * 68 + col + dx] - wv[dy * 3 + dx]);
        v = fmaxf(fmaf(-acc, sc, sf), 0.f);
      }
      sh[c * 396 + i] = v;
    }
  }
  __syncthreads();

  int lane = tid & 63, wid = tid >> 6;
  int r = (tid >> 5) & 3;     // row within band, 0..3
  int x0 = (tid & 31) * 2;    // col span start (8B-aligned LDS reads)
  int oh = __builtin_amdgcn_readfirstlane(tid >> 7);  // og half, wave-uniform
  const float* shbase = &sh[r * 66 + x0];
  __half* a2p = a2 + (size_t)b * 32 * HW + (y0 + r) * 64 + x0;

#pragma unroll 1
  for (int p = 0; p < 2; p++) {
    int ogb = (oh * 2 + p) * 8;  // base output channel of this pass
    float acc[8][2];
#pragma unroll
    for (int o = 0; o < 8; o++) { acc[o][0] = 0.f; acc[o][1] = 0.f; }

    // prefetch activations for c=0
    float2 nx[6];
#pragma unroll
    for (int dy = 0; dy < 3; dy++) {
      const float* rp = shbase + dy * 66;
      nx[dy * 2] = *(const float2*)rp;
      nx[dy * 2 + 1] = *(const float2*)(rp + 2);
    }

#pragma unroll 1
    for (int c = 0; c < 16; c++) {
      float2 cu[6];
#pragma unroll
      for (int j = 0; j < 6; j++) cu[j] = nx[j];
      if (c < 15) {  // issue next-iteration loads before math
        const float* nb = shbase + (c + 1) * 396;
#pragma unroll
        for (int dy = 0; dy < 3; dy++) {
          const float* rp = nb + dy * 66;
          nx[dy * 2] = *(const float2*)rp;
          nx[dy * 2 + 1] = *(const float2*)(rp + 2);
        }
      }
      const float* wc = w2 + ogb * 144 + c * 9;  // uniform -> s_load
#pragma unroll
      for (int o = 0; o < 8; o++) {
        const float* wp = wc + o * 144;
#pragma unroll
        for (int dy = 0; dy < 3; dy++) {
          float w0 = wp[dy * 3], w1v = wp[dy * 3 + 1], w2v = wp[dy * 3 + 2];
          float a0 = cu[dy * 2].x, a1 = cu[dy * 2].y;
          float a2v = cu[dy * 2 + 1].x, a3 = cu[dy * 2 + 1].y;
          acc[o][0] += fabsf(a0 - w0) + fabsf(a1 - w1v) + fabsf(a2v - w2v);
          acc[o][1] += fabsf(a1 - w0) + fabsf(a2v - w1v) + fabsf(a3 - w2v);
        }
      }
    }
    // store (fp16) + per-wave stats partials (fp32-exact)
#pragma unroll
    for (int o = 0; o < 8; o++) {
      float v0 = -acc[o][0], v1 = -acc[o][1];
      *(__half2*)(a2p + (ogb + o) * HW) =
          __halves2half2(__float2half_rn(v0), __float2half_rn(v1));
      float s = v0 + v1, q = v0 * v0 + v1 * v1;
      for (int off = 32; off; off >>= 1) {
        s += __shfl_down(s, off, 64);
        q += __shfl_down(q, off, 64);
      }
      if (lane == 0) {
        red[wid * 32 + p * 16 + o * 2] = s;
        red[wid * 32 + p * 16 + o * 2 + 1] = q;
      }
    }
  }
  __syncthreads();
  if (tid < 32) {
    int oc = tid;
    int og = oc >> 3, o = oc & 7;
    int pp = og & 1, wb = (og >> 1) * 2;  // wave pair owning this og
    float s = red[wb * 32 + pp * 16 + o * 2] + red[(wb + 1) * 32 + pp * 16 + o * 2];
    float q = red[wb * 32 + pp * 16 + o * 2 + 1] + red[(wb + 1) * 32 + pp * 16 + o * 2 + 1];
    atomicAdd(&s2[oc], (double)s);
    atomicAdd(&s2[32 + oc], (double)q);
  }
}

// ---------------- Kernel 3: BN2 (inline params) + ReLU + avgpool + FC -------
__global__ __launch_bounds__(1024) void k_poolfc(const __half* __restrict__ a2,
                                                 const double* __restrict__ s2,
                                                 const float* __restrict__ g2,
                                                 const float* __restrict__ b2,
                                                 const float* __restrict__ fw,
                                                 const float* __restrict__ fb,
                                                 float* __restrict__ out) {
  __shared__ float poolv[32];
  int b = blockIdx.x, tid = threadIdx.x;
  int o = tid >> 5, part = tid & 31;  // 32 threads per channel
  // per-thread inline BN2 params (redundant across the 32 parts, cheap)
  double N = 1048576.0;
  double mean = s2[o] / N;
  double var = s2[32 + o] / N - mean * mean;
  float s = g2[o] * (float)(1.0 / sqrt(var + 1e-5));
  float f = b2[o] - (float)mean * s;
  const float4* p = (const float4*)(a2 + ((size_t)b * 32 + o) * HW);
  float acc = 0.f;
#pragma unroll
  for (int i = 0; i < 16; i++) {  // 16 iters * 32 threads * 8 halves = 4096
    float4 raw = p[i * 32 + part];
    const __half2* hp = (const __half2*)&raw;
#pragma unroll
    for (int k = 0; k < 4; k++) {
      float2 v = __half22float2(hp[k]);
      acc += fmaxf(fmaf(v.x, s, f), 0.f) + fmaxf(fmaf(v.y, s, f), 0.f);
    }
  }
  acc += __shfl_down(acc, 16, 32);
  acc += __shfl_down(acc, 8, 32);
  acc += __shfl_down(acc, 4, 32);
  acc += __shfl_down(acc, 2, 32);
  acc += __shfl_down(acc, 1, 32);
  if (part == 0) poolv[o] = acc * (1.f / 4096.f);
  __syncthreads();
  if (tid < 10) {
    float rr = fb[tid];
#pragma unroll
    for (int oc = 0; oc < 32; oc++) rr += poolv[oc] * fw[tid * 32 + oc];
    out[b * 10 + tid] = rr;
  }
}

extern "C" void kernel_launch(void* const* d_in, const int* in_sizes, int n_in,
                              void* d_out, int out_size, void* d_ws, size_t ws_size,
                              hipStream_t stream) {
  const float* x   = (const float*)d_in[0];
  const float* w1  = (const float*)d_in[1];
  const float* g1  = (const float*)d_in[2];
  const float* b1  = (const float*)d_in[3];
  const float* w2  = (const float*)d_in[4];
  const float* g2  = (const float*)d_in[5];
  const float* b2  = (const float*)d_in[6];
  const float* fcw = (const float*)d_in[7];
  const float* fcb = (const float*)d_in[8];
  float* out = (float*)d_out;

  char* ws = (char*)d_ws;
  __half* a2 = (__half*)ws;                                // 67,108,864 B
  double* stats = (double*)(ws + 67108864);                // 96 doubles
  double* s1 = stats;                                      // sum[16], sq[16]
  double* s2 = stats + 32;                                 // sum[32], sq[32]

  hipMemsetAsync(stats, 0, 768, stream);
  k_stats1<<<256, 256, 0, stream>>>(x, w1, s1);
  k_layer2<<<4096, 256, 0, stream>>>(x, w1, s1, g1, b1, w2, a2, s2);
  k_poolfc<<<256, 1024, 0, stream>>>(a2, s2, g2, b2, fcw, fcb, out);
}